// Round 13
// baseline (140.175 us; speedup 1.0000x reference)
//
#include <hip/hip_runtime.h>
#include <math.h>

// Problem constants
#define B 2
#define S 2048
#define H 8
#define HD 64
#define E 512
#define N3E 1536
#define M 4096
#define HALF 128

typedef unsigned short u16;
typedef unsigned int u32;
using short8 = __attribute__((ext_vector_type(8))) short;
using f32x4  = __attribute__((ext_vector_type(4))) float;

__device__ __forceinline__ u32 bfhi(float v) {
    union { float f; u32 u; } c; c.f = v;
    return (c.u + 0x7fffu + ((c.u >> 16) & 1u)) >> 16;   // RNE
}
__device__ __forceinline__ float bff(u32 b) {
    union { u32 u; float f; } c; c.u = b << 16; return c.f;
}

// ---------------------------------------------------------------------------
// prep_all: fp32 [rows][512] -> hi/lo bf16 MFMA fragments, one launch.
// Tile T = rt*16 + kb; lane ln: row rt*16+(ln&15), k = kb*32+(ln>>4)*8+j.
// Frag addr = (T*64+ln)*8+j. w_o gets hi only (outproj is 1-term).
// ---------------------------------------------------------------------------
__global__ __launch_bounds__(256) void prep_all(
    const float* __restrict__ x,     u16* __restrict__ XAh, u16* __restrict__ XAl,
    const float* __restrict__ wqkv,  u16* __restrict__ WBh, u16* __restrict__ WBl,
    const float* __restrict__ wo,    u16* __restrict__ OBh)
{
    const int wv = threadIdx.x >> 6, ln = threadIdx.x & 63;
    const float* src; u16 *dh, *dl; int Ti; bool wantlo;
    if (blockIdx.x < 1024)      { src = x;    dh = XAh; dl = XAl; Ti = blockIdx.x * 4 + wv; wantlo = true; }
    else if (blockIdx.x < 1408) { src = wqkv; dh = WBh; dl = WBl; Ti = (blockIdx.x - 1024) * 4 + wv; wantlo = true; }
    else                        { src = wo;   dh = OBh; dl = OBh; Ti = (blockIdx.x - 1408) * 4 + wv; wantlo = false; }

    const int rt = Ti >> 4, kb = Ti & 15;
    const int row = rt * 16 + (ln & 15);
    const int kc  = kb * 32 + (ln >> 4) * 8;
    const float4* s = (const float4*)(src + (size_t)row * 512 + kc);
    float4 v0 = s[0], v1 = s[1];
    float f[8] = {v0.x, v0.y, v0.z, v0.w, v1.x, v1.y, v1.z, v1.w};
    short8 hs, ls;
    #pragma unroll
    for (int e = 0; e < 8; ++e) {
        u32 hb = bfhi(f[e]);
        hs[e] = (short)hb;
        ls[e] = (short)bfhi(f[e] - bff(hb));
    }
    const size_t off = (size_t)Ti * 512 + ln * 8;
    *(short8*)(dh + off) = hs;
    if (wantlo) *(short8*)(dl + off) = ls;
}

// ---------------------------------------------------------------------------
// qkv GEMM (LDS-free, pre-built fragments, split-bf16 MFMA).
// Block tile 128(m) x 96(n) via 512 THREADS (8 waves, 4m x 2n); wave =
// 32x48 = 2x3 tiles. Grid (16,32) = 512 blocks = 2 blocks/CU x 8 waves =
// 16 waves/CU = 4 waves/SIMD -- doubles R12's latency hiding WITHOUT the
// R11 launch_bounds min-wave pin (R11's NaN is attributed to that pin; this
// round bisects wave-shape vs pin).
// Precision per n-tile segment: Q/K 3-term, V 1-term hi*hi.
// Epilogue: Qh/Ql [m][h*64+d], Kh/Kl [b][h][s][d], Vth [b][h][d][s] (hi only).
// ---------------------------------------------------------------------------
__global__ __launch_bounds__(512) void qkv_mfma(
    const u16* __restrict__ XAh, const u16* __restrict__ XAl,
    const u16* __restrict__ WBh, const u16* __restrict__ WBl,
    const float* __restrict__ bias,
    u16* __restrict__ Qh, u16* __restrict__ Ql,
    u16* __restrict__ Kh, u16* __restrict__ Kl,
    u16* __restrict__ Vth)
{
    const int wv = threadIdx.x >> 6, ln = threadIdx.x & 63;   // wv 0..7
    const int waveM = wv >> 1, waveN = wv & 1;                 // 4m x 2n
    const int mtb = blockIdx.y * 8 + waveM * 2;   // 2 m-tiles / wave
    const int ntb = blockIdx.x * 6 + waveN * 3;   // 3 n-tiles / wave
    const int lr = ln & 15, lk = ln >> 4;

    // segment type per j-tile (wave-uniform): 0=q 1=k 2=v
    int whj[3];
    #pragma unroll
    for (int j = 0; j < 3; ++j) whj[j] = ((ntb + j) % 12) >> 2;

    f32x4 acc[2][3] = {};

    for (int kb = 0; kb < 16; ++kb) {
        short8 a_h[2], a_l[2], b_h[3], b_l[3];
        #pragma unroll
        for (int i = 0; i < 2; ++i) {
            const size_t o = ((size_t)(mtb + i) * 16 + kb) * 512 + ln * 8;
            a_h[i] = *(const short8*)(XAh + o);
            a_l[i] = *(const short8*)(XAl + o);
        }
        #pragma unroll
        for (int j = 0; j < 3; ++j) {
            const size_t o = ((size_t)(ntb + j) * 16 + kb) * 512 + ln * 8;
            b_h[j] = *(const short8*)(WBh + o);
            if (whj[j] != 2) b_l[j] = *(const short8*)(WBl + o);
        }
        #pragma unroll
        for (int i = 0; i < 2; ++i)
            #pragma unroll
            for (int j = 0; j < 3; ++j) {
                acc[i][j] = __builtin_amdgcn_mfma_f32_16x16x32_bf16(a_h[i], b_h[j], acc[i][j], 0, 0, 0);
                if (whj[j] != 2) {
                    acc[i][j] = __builtin_amdgcn_mfma_f32_16x16x32_bf16(a_h[i], b_l[j], acc[i][j], 0, 0, 0);
                    acc[i][j] = __builtin_amdgcn_mfma_f32_16x16x32_bf16(a_l[i], b_h[j], acc[i][j], 0, 0, 0);
                }
            }
    }

    // epilogue: bias + scatter (C/D: col=lane&15, row=(lane>>4)*4+r)
    #pragma unroll
    for (int j = 0; j < 3; ++j) {
        const int n  = (ntb + j) * 16 + lr;
        const int h  = n / 192;
        const int rr = n % 192;
        const int wh = rr >> 6;     // 0=q 1=k 2=v
        const int d  = rr & 63;
        const float bv = bias[n];
        #pragma unroll
        for (int i = 0; i < 2; ++i) {
            const int mbase = (mtb + i) * 16 + lk * 4;
            const int b_ = mbase >> 11;
            const int s0 = mbase & 2047;
            float v[4];
            u32 hb[4];
            #pragma unroll
            for (int r = 0; r < 4; ++r) {
                v[r] = acc[i][j][r] + bv;
                hb[r] = bfhi(v[r]);
            }
            if (wh == 0) {
                #pragma unroll
                for (int r = 0; r < 4; ++r) {
                    const size_t o = (size_t)(mbase + r) * 512 + h * 64 + d;
                    Qh[o] = (u16)hb[r];
                    Ql[o] = (u16)bfhi(v[r] - bff(hb[r]));
                }
            } else if (wh == 1) {
                #pragma unroll
                for (int r = 0; r < 4; ++r) {
                    const size_t o = ((size_t)(b_ * 8 + h) * 2048 + s0 + r) * 64 + d;
                    Kh[o] = (u16)hb[r];
                    Kl[o] = (u16)bfhi(v[r] - bff(hb[r]));
                }
            } else {
                short4 h4;
                h4.x = (short)hb[0]; h4.y = (short)hb[1];
                h4.z = (short)hb[2]; h4.w = (short)hb[3];
                const size_t o = ((size_t)(b_ * 8 + h) * 64 + d) * 2048 + s0;
                *(short4*)(Vth + o) = h4;
            }
        }
    }
}

// ---------------------------------------------------------------------------
// MFMA banded attention (unchanged, known-good). 512 threads, 32 queries/
// block, bh = blockIdx.x & 15 -> XCD-pinned. LDS ~20 KB -> 4 blocks/CU,
// single round. No max-subtraction (logits ~N(0,1); shift-invariant).
// exp + bf16-snap + row-sum fused into score epilogue. Reference masking
// (band, fp32 score==0, padding, dead row -> 0) on fp32 s before exp.
// PV: one ds_read_b128 per MFMA. Out -> VF A-fragments.
// ---------------------------------------------------------------------------
__global__ __launch_bounds__(512, 8) void attn_mfma(
    const u16* __restrict__ Qh, const u16* __restrict__ Ql,
    const u16* __restrict__ Kh, const u16* __restrict__ Kl,
    const u16* __restrict__ Vth,
    const int* __restrict__ mask, u16* __restrict__ VF)
{
    __shared__ u16   scb[32 * 296];    // P (bf16); stride 296 (16B-aligned rows)
    __shared__ float rowsum[32];
    __shared__ u16   kmsk[288];
    __shared__ int   qmsk[32];

    const int tid = threadIdx.x;
    const int wv = tid >> 6, ln = tid & 63;
    const int lr = ln & 15, lk = ln >> 4;
    const int bh = blockIdx.x & 15;            // XCD-pinned
    const int i0 = (blockIdx.x >> 4) * 32;
    const int b = bh >> 3, h = bh & 7;

    const int klo = max(0, i0 - HALF);
    const int khi = min(S - 1, i0 + 31 + HALF);
    const int kcount = khi - klo + 1;          // multiple of 32, <= 288
    const int nkt = kcount >> 4, nks = kcount >> 5;

    for (int j = tid; j < kcount; j += 512) kmsk[j] = (u16)(mask[b * S + klo + j] != 0);
    if (tid < 32) { qmsk[tid] = mask[b * S + i0 + tid]; rowsum[tid] = 0.f; }
    __syncthreads();

    // wave grouping: waves 0-3 -> mi=0, waves 4-7 -> mi=1
    const int mi = wv >> 2;

    // hoist this wave's Q fragments (A-frag row q = i0 + mi*16 + lr)
    short8 qa_h[2], qa_l[2];
    {
        const int q = i0 + mi * 16 + lr;
        #pragma unroll
        for (int dh = 0; dh < 2; ++dh) {
            const size_t qo = (size_t)(b * S + q) * 512 + h * 64 + dh * 32 + lk * 8;
            qa_h[dh] = *(const short8*)(Qh + qo);
            qa_l[dh] = *(const short8*)(Ql + qo);
        }
    }

    // ---- score phase: MFMA -> mask -> exp -> bf16 P + running row-sums ----
    float psum[4] = {0.f, 0.f, 0.f, 0.f};
    for (int ni = (wv & 3); ni < nkt; ni += 4) {
        const int key = klo + ni * 16 + lr;     // B-frag row = this lane's col
        f32x4 acc = {};
        #pragma unroll
        for (int dh = 0; dh < 2; ++dh) {
            const size_t ko = ((size_t)(b * 8 + h) * 2048 + key) * 64 + dh * 32 + lk * 8;
            short8 bh_ = *(const short8*)(Kh + ko);
            short8 bl_ = *(const short8*)(Kl + ko);
            acc = __builtin_amdgcn_mfma_f32_16x16x32_bf16(qa_h[dh], bh_, acc, 0, 0, 0);
            acc = __builtin_amdgcn_mfma_f32_16x16x32_bf16(qa_h[dh], bl_, acc, 0, 0, 0);
            acc = __builtin_amdgcn_mfma_f32_16x16x32_bf16(qa_l[dh], bh_, acc, 0, 0, 0);
        }
        const bool kok = (kmsk[ni * 16 + lr] != 0);
        #pragma unroll
        for (int r = 0; r < 4; ++r) {
            const int row = mi * 16 + lk * 4 + r;
            const int qr  = i0 + row;
            float s = acc[r] * 0.125f;           // 1/sqrt(64)
            const bool valid = kok && (qmsk[row] != 0)
                               && (qr - key <= HALF) && (key - qr <= HALF)
                               && (s != 0.0f);
            float p = valid ? __expf(s) : 0.f;
            u32 pb = bfhi(p);
            scb[row * 296 + ni * 16 + lr] = (u16)pb;
            psum[r] += bff(pb);
        }
    }
    // reduce partial sums over the 16 columns of each lk group, one atomic each
    #pragma unroll
    for (int off = 1; off <= 8; off <<= 1)
        #pragma unroll
        for (int r = 0; r < 4; ++r)
            psum[r] += __shfl_xor(psum[r], off);
    if (lr == 0) {
        #pragma unroll
        for (int r = 0; r < 4; ++r)
            atomicAdd(&rowsum[mi * 16 + lk * 4 + r], psum[r]);
    }
    __syncthreads();

    // ---- PV phase: 8 waves = (mi: 2) x (d-tile: 4); P via one b128/MFMA ----
    const int d0 = (wv & 3) * 16;
    f32x4 acc2 = {};
    for (int ks = 0; ks < nks; ++ks) {
        short8 pa = *(const short8*)&scb[(mi * 16 + lr) * 296 + ks * 32 + lk * 8];
        const size_t vo = ((size_t)(b * 8 + h) * 64 + d0 + lr) * 2048 + klo + ks * 32 + lk * 8;
        short8 vh = *(const short8*)(Vth + vo);
        acc2 = __builtin_amdgcn_mfma_f32_16x16x32_bf16(pa, vh, acc2, 0, 0, 0);
    }

    // epilogue: divide by rowsum, write VF A-fragments (bf16)
    #pragma unroll
    for (int r = 0; r < 4; ++r) {
        const int row = mi * 16 + lk * 4 + r;
        const float rs = rowsum[row];
        const float inv = (rs > 0.f) ? 1.f / rs : 0.f;
        const int m = b * S + i0 + row;
        const int mt = m >> 4, lrm = m & 15;
        const int e = h * 64 + d0 + lr;
        const int kb = e >> 5, rem = e & 31;
        VF[((size_t)(mt * 16 + kb) * 64 + (rem >> 3) * 16 + lrm) * 8 + (rem & 7)]
            = (u16)bfhi(acc2[r] * inv);
    }
}

// ---------------------------------------------------------------------------
// Output projection: A = VF bf16 frags, B = w_o hi frags (1-term MFMA).
// Block 128x64, grid (8,32) = 256 blocks = 1/CU. Wave = 64x32 = 4x2 tiles.
// ---------------------------------------------------------------------------
__global__ __launch_bounds__(256) void outproj_mfma(
    const u16* __restrict__ VF, const u16* __restrict__ OBh,
    const float* __restrict__ bo, float* __restrict__ out)
{
    const int wv = threadIdx.x >> 6, ln = threadIdx.x & 63;
    const int waveM = wv >> 1, waveN = wv & 1;
    const int mtb = blockIdx.y * 8 + waveM * 4;
    const int ntb = blockIdx.x * 4 + waveN * 2;
    const int lr = ln & 15, lk = ln >> 4;

    f32x4 acc[4][2] = {};

    for (int kb = 0; kb < 16; ++kb) {
        short8 a[4], b_h[2];
        #pragma unroll
        for (int i = 0; i < 4; ++i)
            a[i] = *(const short8*)(VF + ((size_t)(mtb + i) * 16 + kb) * 512 + ln * 8);
        #pragma unroll
        for (int j = 0; j < 2; ++j)
            b_h[j] = *(const short8*)(OBh + ((size_t)(ntb + j) * 16 + kb) * 512 + ln * 8);
        #pragma unroll
        for (int i = 0; i < 4; ++i)
            #pragma unroll
            for (int j = 0; j < 2; ++j)
                acc[i][j] = __builtin_amdgcn_mfma_f32_16x16x32_bf16(a[i], b_h[j], acc[i][j], 0, 0, 0);
    }

    #pragma unroll
    for (int j = 0; j < 2; ++j) {
        const int n = (ntb + j) * 16 + lr;
        const float bv = bo[n];
        #pragma unroll
        for (int i = 0; i < 4; ++i)
            #pragma unroll
            for (int r = 0; r < 4; ++r) {
                const int m = (mtb + i) * 16 + lk * 4 + r;
                out[(size_t)m * 512 + n] = acc[i][j][r] + bv;
            }
    }
}

extern "C" void kernel_launch(void* const* d_in, const int* in_sizes, int n_in,
                              void* d_out, int out_size, void* d_ws, size_t ws_size,
                              hipStream_t stream)
{
    const float* x     = (const float*)d_in[0];   // [B,S,512] fp32
    const int*   pmask = (const int*)d_in[1];     // [B,S] int32
    const float* w_qkv = (const float*)d_in[2];   // [1536,512] fp32
    const float* b_qkv = (const float*)d_in[3];   // [1536] fp32
    const float* w_o   = (const float*)d_in[4];   // [512,512] fp32
    const float* b_o   = (const float*)d_in[5];   // [512] fp32
    float* out = (float*)d_out;                   // [B,S,512] fp32

    // x fragments live in d_out (8 MiB, dead until outproj overwrites it)
    u16* XAh = (u16*)d_out;                       // 4 MiB
    u16* XAl = XAh + (size_t)2097152;             // 4 MiB

    // ws layout (32 MiB budget):
    char* w8 = (char*)d_ws;
    u16* WBh = (u16*)(w8 + 0);                    // 1.5 MiB  w_qkv hi frags
    u16* WBl = (u16*)(w8 + 1572864);              // 1.5 MiB
    u16* OBh = (u16*)(w8 + 3145728);              // 0.5 MiB  w_o hi frags
    u16* Qh  = (u16*)(w8 + 4194304);              // 4 MiB [m][h*64+d]
    u16* Ql  = (u16*)(w8 + 8388608);              // 4 MiB
    u16* Kh  = (u16*)(w8 + 12582912);             // 4 MiB [b][h][s][d]
    u16* Kl  = (u16*)(w8 + 16777216);             // 4 MiB
    u16* Vth = (u16*)(w8 + 20971520);             // 4 MiB [b][h][d][s] (hi only)
    u16* VF  = (u16*)(w8 + 29360128);             // 4 MiB attn-out A-frags

    prep_all<<<1536, 256, 0, stream>>>(x, XAh, XAl, w_qkv, WBh, WBl, w_o, OBh);
    qkv_mfma<<<dim3(16, 32), 512, 0, stream>>>(XAh, XAl, WBh, WBl, b_qkv,
                                               Qh, Ql, Kh, Kl, Vth);
    attn_mfma<<<1024, 512, 0, stream>>>(Qh, Ql, Kh, Kl, Vth, pmask, VF);
    outproj_mfma<<<dim3(8, 32), 256, 0, stream>>>(VF, OBh, b_o, out);
}

// Round 15
// 135.078 us; speedup vs baseline: 1.0377x; 1.0377x over previous
//
#include <hip/hip_runtime.h>
#include <math.h>

// Problem constants
#define B 2
#define S 2048
#define H 8
#define HD 64
#define E 512
#define N3E 1536
#define M 4096
#define HALF 128

typedef unsigned short u16;
typedef unsigned int u32;
using short8 = __attribute__((ext_vector_type(8))) short;
using f32x4  = __attribute__((ext_vector_type(4))) float;

__device__ __forceinline__ u32 bfhi(float v) {
    union { float f; u32 u; } c; c.f = v;
    return (c.u + 0x7fffu + ((c.u >> 16) & 1u)) >> 16;   // RNE
}
__device__ __forceinline__ float bff(u32 b) {
    union { u32 u; float f; } c; c.u = b << 16; return c.f;
}

// ---------------------------------------------------------------------------
// prep_all: fp32 [rows][512] -> hi/lo bf16 MFMA fragments, one launch.
// Tile T = rt*16 + kb; lane ln: row rt*16+(ln&15), k = kb*32+(ln>>4)*8+j.
// Frag addr = (T*64+ln)*8+j. w_o gets hi only (outproj is 1-term).
// ---------------------------------------------------------------------------
__global__ __launch_bounds__(256) void prep_all(
    const float* __restrict__ x,     u16* __restrict__ XAh, u16* __restrict__ XAl,
    const float* __restrict__ wqkv,  u16* __restrict__ WBh, u16* __restrict__ WBl,
    const float* __restrict__ wo,    u16* __restrict__ OBh)
{
    const int wv = threadIdx.x >> 6, ln = threadIdx.x & 63;
    const float* src; u16 *dh, *dl; int Ti; bool wantlo;
    if (blockIdx.x < 1024)      { src = x;    dh = XAh; dl = XAl; Ti = blockIdx.x * 4 + wv; wantlo = true; }
    else if (blockIdx.x < 1408) { src = wqkv; dh = WBh; dl = WBl; Ti = (blockIdx.x - 1024) * 4 + wv; wantlo = true; }
    else                        { src = wo;   dh = OBh; dl = OBh; Ti = (blockIdx.x - 1408) * 4 + wv; wantlo = false; }

    const int rt = Ti >> 4, kb = Ti & 15;
    const int row = rt * 16 + (ln & 15);
    const int kc  = kb * 32 + (ln >> 4) * 8;
    const float4* s = (const float4*)(src + (size_t)row * 512 + kc);
    float4 v0 = s[0], v1 = s[1];
    float f[8] = {v0.x, v0.y, v0.z, v0.w, v1.x, v1.y, v1.z, v1.w};
    short8 hs, ls;
    #pragma unroll
    for (int e = 0; e < 8; ++e) {
        u32 hb = bfhi(f[e]);
        hs[e] = (short)hb;
        ls[e] = (short)bfhi(f[e] - bff(hb));
    }
    const size_t off = (size_t)Ti * 512 + ln * 8;
    *(short8*)(dh + off) = hs;
    if (wantlo) *(short8*)(dl + off) = ls;
}

// ---------------------------------------------------------------------------
// qkv GEMM (R12 body, known-good) + XCD-aware block swizzle.
// 1-D grid 512; lin -> (bx, by) such that xcd(lin)=lin%8 == by%8: all 16
// blocks sharing a by A-panel land on ONE XCD, so the panel is fetched to one
// L2 instead of eight (per-XCD set: 4 A-panels 2 MB + B 3 MB ~ L2-resident).
// Same L2 logic that cut attn FETCH 10x in R7, now applied to qkv.
// Block tile 128(m) x 96(n); 4 waves 2x2; wave = 64x48 = 4x3 tiles.
// Precision per n-tile segment: Q/K 3-term, V 1-term hi*hi.
// Epilogue: Qh/Ql [m][h*64+d], Kh/Kl [b][h][s][d], Vth [b][h][d][s] (hi only).
// ---------------------------------------------------------------------------
__global__ __launch_bounds__(256) void qkv_mfma(
    const u16* __restrict__ XAh, const u16* __restrict__ XAl,
    const u16* __restrict__ WBh, const u16* __restrict__ WBl,
    const float* __restrict__ bias,
    u16* __restrict__ Qh, u16* __restrict__ Ql,
    u16* __restrict__ Kh, u16* __restrict__ Kl,
    u16* __restrict__ Vth)
{
    // swizzle: lin = (by&7) + 8*(bx + 16*(by>>3))  =>  lin%8 == by%8
    const int lin = blockIdx.x;
    const int c = lin & 7, rest = lin >> 3;
    const int bx = rest & 15;
    const int by = (rest >> 4) * 8 + c;

    const int wv = threadIdx.x >> 6, ln = threadIdx.x & 63;
    const int waveM = wv >> 1, waveN = wv & 1;
    const int mtb = by * 8 + waveM * 4;
    const int ntb = bx * 6 + waveN * 3;
    const int lr = ln & 15, lk = ln >> 4;

    // segment type per j-tile (wave-uniform): 0=q 1=k 2=v
    int whj[3];
    #pragma unroll
    for (int j = 0; j < 3; ++j) whj[j] = ((ntb + j) % 12) >> 2;

    f32x4 acc[4][3] = {};

    for (int kb = 0; kb < 16; ++kb) {
        short8 a_h[4], a_l[4], b_h[3], b_l[3];
        #pragma unroll
        for (int i = 0; i < 4; ++i) {
            const size_t o = ((size_t)(mtb + i) * 16 + kb) * 512 + ln * 8;
            a_h[i] = *(const short8*)(XAh + o);
            a_l[i] = *(const short8*)(XAl + o);
        }
        #pragma unroll
        for (int j = 0; j < 3; ++j) {
            const size_t o = ((size_t)(ntb + j) * 16 + kb) * 512 + ln * 8;
            b_h[j] = *(const short8*)(WBh + o);
            if (whj[j] != 2) b_l[j] = *(const short8*)(WBl + o);
        }
        #pragma unroll
        for (int i = 0; i < 4; ++i)
            #pragma unroll
            for (int j = 0; j < 3; ++j) {
                acc[i][j] = __builtin_amdgcn_mfma_f32_16x16x32_bf16(a_h[i], b_h[j], acc[i][j], 0, 0, 0);
                if (whj[j] != 2) {
                    acc[i][j] = __builtin_amdgcn_mfma_f32_16x16x32_bf16(a_h[i], b_l[j], acc[i][j], 0, 0, 0);
                    acc[i][j] = __builtin_amdgcn_mfma_f32_16x16x32_bf16(a_l[i], b_h[j], acc[i][j], 0, 0, 0);
                }
            }
    }

    // epilogue: bias + scatter (C/D: col=lane&15, row=(lane>>4)*4+r)
    #pragma unroll
    for (int j = 0; j < 3; ++j) {
        const int n  = (ntb + j) * 16 + lr;
        const int h  = n / 192;
        const int rr = n % 192;
        const int wh = rr >> 6;     // 0=q 1=k 2=v
        const int d  = rr & 63;
        const float bv = bias[n];
        #pragma unroll
        for (int i = 0; i < 4; ++i) {
            const int mbase = (mtb + i) * 16 + lk * 4;
            const int b_ = mbase >> 11;
            const int s0 = mbase & 2047;
            float v[4];
            u32 hb[4];
            #pragma unroll
            for (int r = 0; r < 4; ++r) {
                v[r] = acc[i][j][r] + bv;
                hb[r] = bfhi(v[r]);
            }
            if (wh == 0) {
                #pragma unroll
                for (int r = 0; r < 4; ++r) {
                    const size_t o = (size_t)(mbase + r) * 512 + h * 64 + d;
                    Qh[o] = (u16)hb[r];
                    Ql[o] = (u16)bfhi(v[r] - bff(hb[r]));
                }
            } else if (wh == 1) {
                #pragma unroll
                for (int r = 0; r < 4; ++r) {
                    const size_t o = ((size_t)(b_ * 8 + h) * 2048 + s0 + r) * 64 + d;
                    Kh[o] = (u16)hb[r];
                    Kl[o] = (u16)bfhi(v[r] - bff(hb[r]));
                }
            } else {
                short4 h4;
                h4.x = (short)hb[0]; h4.y = (short)hb[1];
                h4.z = (short)hb[2]; h4.w = (short)hb[3];
                const size_t o = ((size_t)(b_ * 8 + h) * 64 + d) * 2048 + s0;
                *(short4*)(Vth + o) = h4;
            }
        }
    }
}

// ---------------------------------------------------------------------------
// MFMA banded attention (unchanged, known-good). 512 threads, 32 queries/
// block, bh = blockIdx.x & 15 -> XCD-pinned. LDS ~20 KB -> 4 blocks/CU,
// single round. No max-subtraction (logits ~N(0,1); shift-invariant).
// exp + bf16-snap + row-sum fused into score epilogue. Reference masking
// (band, fp32 score==0, padding, dead row -> 0) on fp32 s before exp.
// PV: one ds_read_b128 per MFMA. Out -> VF A-fragments.
// ---------------------------------------------------------------------------
__global__ __launch_bounds__(512, 8) void attn_mfma(
    const u16* __restrict__ Qh, const u16* __restrict__ Ql,
    const u16* __restrict__ Kh, const u16* __restrict__ Kl,
    const u16* __restrict__ Vth,
    const int* __restrict__ mask, u16* __restrict__ VF)
{
    __shared__ u16   scb[32 * 296];    // P (bf16); stride 296 (16B-aligned rows)
    __shared__ float rowsum[32];
    __shared__ u16   kmsk[288];
    __shared__ int   qmsk[32];

    const int tid = threadIdx.x;
    const int wv = tid >> 6, ln = tid & 63;
    const int lr = ln & 15, lk = ln >> 4;
    const int bh = blockIdx.x & 15;            // XCD-pinned
    const int i0 = (blockIdx.x >> 4) * 32;
    const int b = bh >> 3, h = bh & 7;

    const int klo = max(0, i0 - HALF);
    const int khi = min(S - 1, i0 + 31 + HALF);
    const int kcount = khi - klo + 1;          // multiple of 32, <= 288
    const int nkt = kcount >> 4, nks = kcount >> 5;

    for (int j = tid; j < kcount; j += 512) kmsk[j] = (u16)(mask[b * S + klo + j] != 0);
    if (tid < 32) { qmsk[tid] = mask[b * S + i0 + tid]; rowsum[tid] = 0.f; }
    __syncthreads();

    // wave grouping: waves 0-3 -> mi=0, waves 4-7 -> mi=1
    const int mi = wv >> 2;

    // hoist this wave's Q fragments (A-frag row q = i0 + mi*16 + lr)
    short8 qa_h[2], qa_l[2];
    {
        const int q = i0 + mi * 16 + lr;
        #pragma unroll
        for (int dh = 0; dh < 2; ++dh) {
            const size_t qo = (size_t)(b * S + q) * 512 + h * 64 + dh * 32 + lk * 8;
            qa_h[dh] = *(const short8*)(Qh + qo);
            qa_l[dh] = *(const short8*)(Ql + qo);
        }
    }

    // ---- score phase: MFMA -> mask -> exp -> bf16 P + running row-sums ----
    float psum[4] = {0.f, 0.f, 0.f, 0.f};
    for (int ni = (wv & 3); ni < nkt; ni += 4) {
        const int key = klo + ni * 16 + lr;     // B-frag row = this lane's col
        f32x4 acc = {};
        #pragma unroll
        for (int dh = 0; dh < 2; ++dh) {
            const size_t ko = ((size_t)(b * 8 + h) * 2048 + key) * 64 + dh * 32 + lk * 8;
            short8 bh_ = *(const short8*)(Kh + ko);
            short8 bl_ = *(const short8*)(Kl + ko);
            acc = __builtin_amdgcn_mfma_f32_16x16x32_bf16(qa_h[dh], bh_, acc, 0, 0, 0);
            acc = __builtin_amdgcn_mfma_f32_16x16x32_bf16(qa_h[dh], bl_, acc, 0, 0, 0);
            acc = __builtin_amdgcn_mfma_f32_16x16x32_bf16(qa_l[dh], bh_, acc, 0, 0, 0);
        }
        const bool kok = (kmsk[ni * 16 + lr] != 0);
        #pragma unroll
        for (int r = 0; r < 4; ++r) {
            const int row = mi * 16 + lk * 4 + r;
            const int qr  = i0 + row;
            float s = acc[r] * 0.125f;           // 1/sqrt(64)
            const bool valid = kok && (qmsk[row] != 0)
                               && (qr - key <= HALF) && (key - qr <= HALF)
                               && (s != 0.0f);
            float p = valid ? __expf(s) : 0.f;
            u32 pb = bfhi(p);
            scb[row * 296 + ni * 16 + lr] = (u16)pb;
            psum[r] += bff(pb);
        }
    }
    // reduce partial sums over the 16 columns of each lk group, one atomic each
    #pragma unroll
    for (int off = 1; off <= 8; off <<= 1)
        #pragma unroll
        for (int r = 0; r < 4; ++r)
            psum[r] += __shfl_xor(psum[r], off);
    if (lr == 0) {
        #pragma unroll
        for (int r = 0; r < 4; ++r)
            atomicAdd(&rowsum[mi * 16 + lk * 4 + r], psum[r]);
    }
    __syncthreads();

    // ---- PV phase: 8 waves = (mi: 2) x (d-tile: 4); P via one b128/MFMA ----
    const int d0 = (wv & 3) * 16;
    f32x4 acc2 = {};
    for (int ks = 0; ks < nks; ++ks) {
        short8 pa = *(const short8*)&scb[(mi * 16 + lr) * 296 + ks * 32 + lk * 8];
        const size_t vo = ((size_t)(b * 8 + h) * 64 + d0 + lr) * 2048 + klo + ks * 32 + lk * 8;
        short8 vh = *(const short8*)(Vth + vo);
        acc2 = __builtin_amdgcn_mfma_f32_16x16x32_bf16(pa, vh, acc2, 0, 0, 0);
    }

    // epilogue: divide by rowsum, write VF A-fragments (bf16)
    #pragma unroll
    for (int r = 0; r < 4; ++r) {
        const int row = mi * 16 + lk * 4 + r;
        const float rs = rowsum[row];
        const float inv = (rs > 0.f) ? 1.f / rs : 0.f;
        const int m = b * S + i0 + row;
        const int mt = m >> 4, lrm = m & 15;
        const int e = h * 64 + d0 + lr;
        const int kb = e >> 5, rem = e & 31;
        VF[((size_t)(mt * 16 + kb) * 64 + (rem >> 3) * 16 + lrm) * 8 + (rem & 7)]
            = (u16)bfhi(acc2[r] * inv);
    }
}

// ---------------------------------------------------------------------------
// Output projection: A = VF bf16 frags, B = w_o hi frags (1-term MFMA),
// with the same XCD swizzle (lin%8 == by%8) so each by's VF panel is fetched
// to one L2. 1-D grid 256; block 128x64; wave = 64x32 = 4x2 tiles.
// ---------------------------------------------------------------------------
__global__ __launch_bounds__(256) void outproj_mfma(
    const u16* __restrict__ VF, const u16* __restrict__ OBh,
    const float* __restrict__ bo, float* __restrict__ out)
{
    // swizzle: lin = (by&7) + 8*(bx + 8*(by>>3))  =>  lin%8 == by%8
    const int lin = blockIdx.x;
    const int c = lin & 7, rest = lin >> 3;
    const int bx = rest & 7;
    const int by = (rest >> 3) * 8 + c;

    const int wv = threadIdx.x >> 6, ln = threadIdx.x & 63;
    const int waveM = wv >> 1, waveN = wv & 1;
    const int mtb = by * 8 + waveM * 4;
    const int ntb = bx * 4 + waveN * 2;
    const int lr = ln & 15, lk = ln >> 4;

    f32x4 acc[4][2] = {};

    for (int kb = 0; kb < 16; ++kb) {
        short8 a[4], b_h[2];
        #pragma unroll
        for (int i = 0; i < 4; ++i)
            a[i] = *(const short8*)(VF + ((size_t)(mtb + i) * 16 + kb) * 512 + ln * 8);
        #pragma unroll
        for (int j = 0; j < 2; ++j)
            b_h[j] = *(const short8*)(OBh + ((size_t)(ntb + j) * 16 + kb) * 512 + ln * 8);
        #pragma unroll
        for (int i = 0; i < 4; ++i)
            #pragma unroll
            for (int j = 0; j < 2; ++j)
                acc[i][j] = __builtin_amdgcn_mfma_f32_16x16x32_bf16(a[i], b_h[j], acc[i][j], 0, 0, 0);
    }

    #pragma unroll
    for (int j = 0; j < 2; ++j) {
        const int n = (ntb + j) * 16 + lr;
        const float bv = bo[n];
        #pragma unroll
        for (int i = 0; i < 4; ++i)
            #pragma unroll
            for (int r = 0; r < 4; ++r) {
                const int m = (mtb + i) * 16 + lk * 4 + r;
                out[(size_t)m * 512 + n] = acc[i][j][r] + bv;
            }
    }
}

extern "C" void kernel_launch(void* const* d_in, const int* in_sizes, int n_in,
                              void* d_out, int out_size, void* d_ws, size_t ws_size,
                              hipStream_t stream)
{
    const float* x     = (const float*)d_in[0];   // [B,S,512] fp32
    const int*   pmask = (const int*)d_in[1];     // [B,S] int32
    const float* w_qkv = (const float*)d_in[2];   // [1536,512] fp32
    const float* b_qkv = (const float*)d_in[3];   // [1536] fp32
    const float* w_o   = (const float*)d_in[4];   // [512,512] fp32
    const float* b_o   = (const float*)d_in[5];   // [512] fp32
    float* out = (float*)d_out;                   // [B,S,512] fp32

    // x fragments live in d_out (8 MiB, dead until outproj overwrites it)
    u16* XAh = (u16*)d_out;                       // 4 MiB
    u16* XAl = XAh + (size_t)2097152;             // 4 MiB

    // ws layout (32 MiB budget):
    char* w8 = (char*)d_ws;
    u16* WBh = (u16*)(w8 + 0);                    // 1.5 MiB  w_qkv hi frags
    u16* WBl = (u16*)(w8 + 1572864);              // 1.5 MiB
    u16* OBh = (u16*)(w8 + 3145728);              // 0.5 MiB  w_o hi frags
    u16* Qh  = (u16*)(w8 + 4194304);              // 4 MiB [m][h*64+d]
    u16* Ql  = (u16*)(w8 + 8388608);              // 4 MiB
    u16* Kh  = (u16*)(w8 + 12582912);             // 4 MiB [b][h][s][d]
    u16* Kl  = (u16*)(w8 + 16777216);             // 4 MiB
    u16* Vth = (u16*)(w8 + 20971520);             // 4 MiB [b][h][d][s] (hi only)
    u16* VF  = (u16*)(w8 + 29360128);             // 4 MiB attn-out A-frags

    prep_all<<<1536, 256, 0, stream>>>(x, XAh, XAl, w_qkv, WBh, WBl, w_o, OBh);
    qkv_mfma<<<512, 256, 0, stream>>>(XAh, XAl, WBh, WBl, b_qkv,
                                      Qh, Ql, Kh, Kl, Vth);
    attn_mfma<<<1024, 512, 0, stream>>>(Qh, Ql, Kh, Kl, Vth, pmask, VF);
    outproj_mfma<<<256, 256, 0, stream>>>(VF, OBh, b_o, out);
}

// Round 16
// 117.968 us; speedup vs baseline: 1.1882x; 1.1450x over previous
//
#include <hip/hip_runtime.h>
#include <math.h>

// Problem constants
#define B 2
#define S 2048
#define H 8
#define HD 64
#define E 512
#define N3E 1536
#define M 4096
#define HALF 128

typedef unsigned short u16;
typedef unsigned int u32;
using short8 = __attribute__((ext_vector_type(8))) short;
using f32x4  = __attribute__((ext_vector_type(4))) float;

__device__ __forceinline__ u32 bfhi(float v) {
    union { float f; u32 u; } c; c.f = v;
    return (c.u + 0x7fffu + ((c.u >> 16) & 1u)) >> 16;   // RNE
}
__device__ __forceinline__ float bff(u32 b) {
    union { u32 u; float f; } c; c.u = b << 16; return c.f;
}

// ---------------------------------------------------------------------------
// PRECISION MODEL (R16): plain bf16 (hi-only) everywhere. Error budget:
// hi-only x,w in the qkv GEMM gives dq ~ 0.4%; logit noise sigma ~ 0.006;
// softmax normalization cancels common-mode and attenuates differential by
// sqrt(sum P^2) ~ 0.08 -> output contribution ~ 0.003 max, under the
// measured 0.0039 floor (VF/w_o bf16 rounding). R10/R12 precision drops
// left absmax bit-identical, corroborating the model.
// ---------------------------------------------------------------------------

// ---------------------------------------------------------------------------
// prep_all: fp32 [rows][512] -> bf16 (hi) MFMA fragments, one launch.
// Tile T = rt*16 + kb; lane ln: row rt*16+(ln&15), k = kb*32+(ln>>4)*8+j.
// Frag addr = (T*64+ln)*8+j.
// ---------------------------------------------------------------------------
__global__ __launch_bounds__(256) void prep_all(
    const float* __restrict__ x,    u16* __restrict__ XAh,
    const float* __restrict__ wqkv, u16* __restrict__ WBh,
    const float* __restrict__ wo,   u16* __restrict__ OBh)
{
    const int wv = threadIdx.x >> 6, ln = threadIdx.x & 63;
    const float* src; u16* dh; int Ti;
    if (blockIdx.x < 1024)      { src = x;    dh = XAh; Ti = blockIdx.x * 4 + wv; }
    else if (blockIdx.x < 1408) { src = wqkv; dh = WBh; Ti = (blockIdx.x - 1024) * 4 + wv; }
    else                        { src = wo;   dh = OBh; Ti = (blockIdx.x - 1408) * 4 + wv; }

    const int rt = Ti >> 4, kb = Ti & 15;
    const int row = rt * 16 + (ln & 15);
    const int kc  = kb * 32 + (ln >> 4) * 8;
    const float4* s = (const float4*)(src + (size_t)row * 512 + kc);
    float4 v0 = s[0], v1 = s[1];
    float f[8] = {v0.x, v0.y, v0.z, v0.w, v1.x, v1.y, v1.z, v1.w};
    short8 hs;
    #pragma unroll
    for (int e = 0; e < 8; ++e) hs[e] = (short)bfhi(f[e]);
    *(short8*)(dh + (size_t)Ti * 512 + ln * 8) = hs;
}

// ---------------------------------------------------------------------------
// qkv GEMM, plain bf16 1-term MFMA (12 MFMA + 7 b128 loads per kb per wave
// vs the old split's ~28 + 13). XCD swizzle kept (lin%8 == by%8).
// NEW: padding masks folded in here -- masked Q/K rows are stored as 0.0
// (post-bias), so in attn a masked key gives s = +/-0 which the reference's
// own `score==0 -> -inf` rule already handles; padded queries give all-zero
// rows -> rowsum 0 -> output 0. attn needs NO mask logic beyond the band.
// Block tile 128(m) x 96(n); 4 waves 2x2; wave = 64x48 = 4x3 tiles.
// Epilogue: Qh [m][h*64+d], Kh [b][h][s][d], Vth [b][h][d][s].
// ---------------------------------------------------------------------------
__global__ __launch_bounds__(256) void qkv_mfma(
    const u16* __restrict__ XAh, const u16* __restrict__ WBh,
    const float* __restrict__ bias, const int* __restrict__ mask,
    u16* __restrict__ Qh, u16* __restrict__ Kh, u16* __restrict__ Vth)
{
    // swizzle: lin = (by&7) + 8*(bx + 16*(by>>3))  =>  lin%8 == by%8
    const int lin = blockIdx.x;
    const int c = lin & 7, rest = lin >> 3;
    const int bx = rest & 15;
    const int by = (rest >> 4) * 8 + c;

    const int wv = threadIdx.x >> 6, ln = threadIdx.x & 63;
    const int waveM = wv >> 1, waveN = wv & 1;
    const int mtb = by * 8 + waveM * 4;
    const int ntb = bx * 6 + waveN * 3;
    const int lr = ln & 15, lk = ln >> 4;

    f32x4 acc[4][3] = {};

    for (int kb = 0; kb < 16; ++kb) {
        short8 a_h[4], b_h[3];
        #pragma unroll
        for (int i = 0; i < 4; ++i)
            a_h[i] = *(const short8*)(XAh + ((size_t)(mtb + i) * 16 + kb) * 512 + ln * 8);
        #pragma unroll
        for (int j = 0; j < 3; ++j)
            b_h[j] = *(const short8*)(WBh + ((size_t)(ntb + j) * 16 + kb) * 512 + ln * 8);
        #pragma unroll
        for (int i = 0; i < 4; ++i)
            #pragma unroll
            for (int j = 0; j < 3; ++j)
                acc[i][j] = __builtin_amdgcn_mfma_f32_16x16x32_bf16(a_h[i], b_h[j], acc[i][j], 0, 0, 0);
    }

    // row masks for this thread's 16 m-rows (Q/K zeroing)
    int rmask[4][4];
    #pragma unroll
    for (int i = 0; i < 4; ++i) {
        const int mb = (mtb + i) * 16 + lk * 4;
        #pragma unroll
        for (int r = 0; r < 4; ++r) rmask[i][r] = mask[mb + r];
    }

    // epilogue: bias + mask-zero + scatter (C/D: col=lane&15, row=(lane>>4)*4+r)
    #pragma unroll
    for (int j = 0; j < 3; ++j) {
        const int n  = (ntb + j) * 16 + lr;
        const int h  = n / 192;
        const int rr = n % 192;
        const int wh = rr >> 6;     // 0=q 1=k 2=v
        const int d  = rr & 63;
        const float bv = bias[n];
        #pragma unroll
        for (int i = 0; i < 4; ++i) {
            const int mbase = (mtb + i) * 16 + lk * 4;
            const int b_ = mbase >> 11;
            const int s0 = mbase & 2047;
            u32 hb[4];
            #pragma unroll
            for (int r = 0; r < 4; ++r) {
                float val = acc[i][j][r] + bv;
                if (wh < 2 && rmask[i][r] == 0) val = 0.f;   // mask folded here
                hb[r] = bfhi(val);
            }
            if (wh == 0) {
                #pragma unroll
                for (int r = 0; r < 4; ++r)
                    Qh[(size_t)(mbase + r) * 512 + h * 64 + d] = (u16)hb[r];
            } else if (wh == 1) {
                #pragma unroll
                for (int r = 0; r < 4; ++r)
                    Kh[((size_t)(b_ * 8 + h) * 2048 + s0 + r) * 64 + d] = (u16)hb[r];
            } else {
                short4 h4;
                h4.x = (short)hb[0]; h4.y = (short)hb[1];
                h4.z = (short)hb[2]; h4.w = (short)hb[3];
                *(short4*)(Vth + ((size_t)(b_ * 8 + h) * 64 + d) * 2048 + s0) = h4;
            }
        }
    }
}

// ---------------------------------------------------------------------------
// MFMA banded attention, bf16 score path. 512 threads, 32 queries/block,
// bh = blockIdx.x & 15 -> XCD-pinned. LDS ~19 KB -> 4 blocks/CU, one round.
// Score per ni: 2 Kh b128 loads + 2 MFMAs (was 4+6). Masking: padded rows
// arrive as zeros from qkv -> s == +/-0 -> excluded by the reference's
// score==0 rule; only the band check remains (one unsigned compare).
// No max-subtraction (logits ~N(0,1); softmax shift-invariant).
// PV: P(bf16 from LDS, one b128/MFMA) x V(bf16). Out -> VF A-fragments.
// ---------------------------------------------------------------------------
__global__ __launch_bounds__(512, 8) void attn_mfma(
    const u16* __restrict__ Qh, const u16* __restrict__ Kh,
    const u16* __restrict__ Vth, u16* __restrict__ VF)
{
    __shared__ u16   scb[32 * 296];    // P (bf16); stride 296 (16B-aligned rows)
    __shared__ float rowsum[32];

    const int tid = threadIdx.x;
    const int wv = tid >> 6, ln = tid & 63;
    const int lr = ln & 15, lk = ln >> 4;
    const int bh = blockIdx.x & 15;            // XCD-pinned
    const int i0 = (blockIdx.x >> 4) * 32;
    const int b = bh >> 3, h = bh & 7;

    const int klo = max(0, i0 - HALF);
    const int khi = min(S - 1, i0 + 31 + HALF);
    const int kcount = khi - klo + 1;          // multiple of 32, <= 288
    const int nkt = kcount >> 4, nks = kcount >> 5;

    if (tid < 32) rowsum[tid] = 0.f;
    __syncthreads();

    // wave grouping: waves 0-3 -> mi=0, waves 4-7 -> mi=1
    const int mi = wv >> 2;

    // hoist this wave's Q fragments (A-frag row q = i0 + mi*16 + lr)
    short8 qa_h[2];
    {
        const int q = i0 + mi * 16 + lr;
        #pragma unroll
        for (int dh = 0; dh < 2; ++dh)
            qa_h[dh] = *(const short8*)(Qh + (size_t)(b * S + q) * 512 + h * 64 + dh * 32 + lk * 8);
    }

    // ---- score phase: MFMA -> band+zero mask -> exp -> bf16 P + row-sums ----
    float psum[4] = {0.f, 0.f, 0.f, 0.f};
    for (int ni = (wv & 3); ni < nkt; ni += 4) {
        const int key = klo + ni * 16 + lr;     // B-frag row = this lane's col
        f32x4 acc = {};
        #pragma unroll
        for (int dh = 0; dh < 2; ++dh) {
            short8 kh_ = *(const short8*)(Kh + ((size_t)(b * 8 + h) * 2048 + key) * 64 + dh * 32 + lk * 8);
            acc = __builtin_amdgcn_mfma_f32_16x16x32_bf16(qa_h[dh], kh_, acc, 0, 0, 0);
        }
        #pragma unroll
        for (int r = 0; r < 4; ++r) {
            const int row = mi * 16 + lk * 4 + r;
            const int qr  = i0 + row;
            float s = acc[r] * 0.125f;           // 1/sqrt(64)
            const bool valid = ((u32)(key - qr + HALF) <= 2 * HALF) && (s != 0.0f);
            float p = valid ? __expf(s) : 0.f;
            u32 pb = bfhi(p);
            scb[row * 296 + ni * 16 + lr] = (u16)pb;
            psum[r] += bff(pb);
        }
    }
    // reduce partial sums over the 16 columns of each lk group, one atomic each
    #pragma unroll
    for (int off = 1; off <= 8; off <<= 1)
        #pragma unroll
        for (int r = 0; r < 4; ++r)
            psum[r] += __shfl_xor(psum[r], off);
    if (lr == 0) {
        #pragma unroll
        for (int r = 0; r < 4; ++r)
            atomicAdd(&rowsum[mi * 16 + lk * 4 + r], psum[r]);
    }
    __syncthreads();

    // ---- PV phase: 8 waves = (mi: 2) x (d-tile: 4); P via one b128/MFMA ----
    const int d0 = (wv & 3) * 16;
    f32x4 acc2 = {};
    for (int ks = 0; ks < nks; ++ks) {
        short8 pa = *(const short8*)&scb[(mi * 16 + lr) * 296 + ks * 32 + lk * 8];
        const size_t vo = ((size_t)(b * 8 + h) * 64 + d0 + lr) * 2048 + klo + ks * 32 + lk * 8;
        short8 vh = *(const short8*)(Vth + vo);
        acc2 = __builtin_amdgcn_mfma_f32_16x16x32_bf16(pa, vh, acc2, 0, 0, 0);
    }

    // epilogue: divide by rowsum, write VF A-fragments (bf16)
    #pragma unroll
    for (int r = 0; r < 4; ++r) {
        const int row = mi * 16 + lk * 4 + r;
        const float rs = rowsum[row];
        const float inv = (rs > 0.f) ? 1.f / rs : 0.f;
        const int m = b * S + i0 + row;
        const int mt = m >> 4, lrm = m & 15;
        const int e = h * 64 + d0 + lr;
        const int kb = e >> 5, rem = e & 31;
        VF[((size_t)(mt * 16 + kb) * 64 + (rem >> 3) * 16 + lrm) * 8 + (rem & 7)]
            = (u16)bfhi(acc2[r] * inv);
    }
}

// ---------------------------------------------------------------------------
// Output projection: A = VF bf16 frags, B = w_o hi frags (1-term MFMA),
// XCD swizzle (lin%8 == by%8). 1-D grid 256; block 128x64; wave 4x2 tiles.
// ---------------------------------------------------------------------------
__global__ __launch_bounds__(256) void outproj_mfma(
    const u16* __restrict__ VF, const u16* __restrict__ OBh,
    const float* __restrict__ bo, float* __restrict__ out)
{
    // swizzle: lin = (by&7) + 8*(bx + 8*(by>>3))  =>  lin%8 == by%8
    const int lin = blockIdx.x;
    const int c = lin & 7, rest = lin >> 3;
    const int bx = rest & 7;
    const int by = (rest >> 3) * 8 + c;

    const int wv = threadIdx.x >> 6, ln = threadIdx.x & 63;
    const int waveM = wv >> 1, waveN = wv & 1;
    const int mtb = by * 8 + waveM * 4;
    const int ntb = bx * 4 + waveN * 2;
    const int lr = ln & 15, lk = ln >> 4;

    f32x4 acc[4][2] = {};

    for (int kb = 0; kb < 16; ++kb) {
        short8 a[4], b_h[2];
        #pragma unroll
        for (int i = 0; i < 4; ++i)
            a[i] = *(const short8*)(VF + ((size_t)(mtb + i) * 16 + kb) * 512 + ln * 8);
        #pragma unroll
        for (int j = 0; j < 2; ++j)
            b_h[j] = *(const short8*)(OBh + ((size_t)(ntb + j) * 16 + kb) * 512 + ln * 8);
        #pragma unroll
        for (int i = 0; i < 4; ++i)
            #pragma unroll
            for (int j = 0; j < 2; ++j)
                acc[i][j] = __builtin_amdgcn_mfma_f32_16x16x32_bf16(a[i], b_h[j], acc[i][j], 0, 0, 0);
    }

    #pragma unroll
    for (int j = 0; j < 2; ++j) {
        const int n = (ntb + j) * 16 + lr;
        const float bv = bo[n];
        #pragma unroll
        for (int i = 0; i < 4; ++i)
            #pragma unroll
            for (int r = 0; r < 4; ++r) {
                const int m = (mtb + i) * 16 + lk * 4 + r;
                out[(size_t)m * 512 + n] = acc[i][j][r] + bv;
            }
    }
}

extern "C" void kernel_launch(void* const* d_in, const int* in_sizes, int n_in,
                              void* d_out, int out_size, void* d_ws, size_t ws_size,
                              hipStream_t stream)
{
    const float* x     = (const float*)d_in[0];   // [B,S,512] fp32
    const int*   pmask = (const int*)d_in[1];     // [B,S] int32
    const float* w_qkv = (const float*)d_in[2];   // [1536,512] fp32
    const float* b_qkv = (const float*)d_in[3];   // [1536] fp32
    const float* w_o   = (const float*)d_in[4];   // [512,512] fp32
    const float* b_o   = (const float*)d_in[5];   // [512] fp32
    float* out = (float*)d_out;                   // [B,S,512] fp32

    // x fragments live in d_out (4 MiB, dead until outproj overwrites it)
    u16* XAh = (u16*)d_out;

    // ws layout (32 MiB budget; lo-fragment slots retired):
    char* w8 = (char*)d_ws;
    u16* WBh = (u16*)(w8 + 0);                    // 1.5 MiB  w_qkv hi frags
    u16* OBh = (u16*)(w8 + 3145728);              // 0.5 MiB  w_o hi frags
    u16* Qh  = (u16*)(w8 + 4194304);              // 4 MiB [m][h*64+d]
    u16* Kh  = (u16*)(w8 + 12582912);             // 4 MiB [b][h][s][d]
    u16* Vth = (u16*)(w8 + 20971520);             // 4 MiB [b][h][d][s]
    u16* VF  = (u16*)(w8 + 29360128);             // 4 MiB attn-out A-frags

    prep_all<<<1536, 256, 0, stream>>>(x, XAh, w_qkv, WBh, w_o, OBh);
    qkv_mfma<<<512, 256, 0, stream>>>(XAh, WBh, b_qkv, pmask, Qh, Kh, Vth);
    attn_mfma<<<1024, 512, 0, stream>>>(Qh, Kh, Vth, VF);
    outproj_mfma<<<256, 256, 0, stream>>>(VF, OBh, b_o, out);
}